// Round 1
// 178.763 us; speedup vs baseline: 1.1176x; 1.1176x over previous
//
#include <hip/hip_runtime.h>
#include <math.h>

typedef unsigned short ushort_t;
typedef __attribute__((ext_vector_type(8))) short bf16x8;
typedef __attribute__((ext_vector_type(4))) short bf16x4;
typedef __attribute__((ext_vector_type(4))) float f32x4;
typedef __attribute__((ext_vector_type(8))) unsigned short u16x8;
typedef __attribute__((ext_vector_type(2))) unsigned int u32x2;
typedef __attribute__((ext_vector_type(4))) unsigned int u32x4;

#define N_TOK 65536
#define DIN 128
#define HD 256
#define DOUT 128
#define NEXP 8
#define MT 64
#define MAX_TILES (N_TOK / MT) /* 1024 */

__device__ __forceinline__ unsigned short f2bf(float f) {
    union { float f; unsigned int i; } v; v.f = f;
    unsigned int i = v.i;
    return (unsigned short)((i + 0x7FFFu + ((i >> 16) & 1u)) >> 16); // RNE
}

#define RT_BLOCK 512
#define RT_TPB 64   /* tokens per block */

// ---------------------------------------------------------------------------
// Fused router + weight-pack + out-init.
//  - router: 8 lanes/token, expert-split logits, top-2 + softmax, two-phase
//    block-counting scatter into per-expert compacted lists (unchanged).
//  - blocks 0..199: pack fp32 W1/W2/Wo into bf16 MFMA B-fragment order
//    (1 chunk of 8 bf16 per thread; same id->chunk map as the old kernel).
//  - every block: init its own 64 out rows with broadcast bo (weights sum
//    to 1, bo added once) -> removes the separate init_out dispatch.
// ---------------------------------------------------------------------------
__global__ __launch_bounds__(RT_BLOCK)
void router_kernel(const float* __restrict__ x,
                   const float* __restrict__ Wg,
                   const float* __restrict__ W1,
                   const float* __restrict__ W2,
                   const float* __restrict__ Wo,
                   const float* __restrict__ bo,
                   int* __restrict__ counts,
                   int* __restrict__ list_tok,
                   float* __restrict__ list_w,
                   ushort_t* __restrict__ wt1f,
                   ushort_t* __restrict__ wt2f,
                   ushort_t* __restrict__ wotf,
                   float* __restrict__ out) {
    __shared__ float wgsT[NEXP * 132]; // padded leading dim: conflict-free b128
    __shared__ int lcnt[NEXP];
    __shared__ int lbase[NEXP];
    int tid = threadIdx.x;
    if (tid < NEXP) lcnt[tid] = 0;
    for (int i = tid; i < DIN * NEXP; i += RT_BLOCK) {
        int ee = i & 7, k = i >> 3;   // Wg[k][e]
        wgsT[ee * 132 + k] = Wg[i];
    }
    // fused init_out: this block's 64 tokens
    {
        const float4* bo4 = (const float4*)bo;
        float4* ob = (float4*)(out + (size_t)blockIdx.x * RT_TPB * DOUT);
#pragma unroll
        for (int i = 0; i < 4; i++) {
            int idx = i * RT_BLOCK + tid;       // 0..2047
            ob[idx] = bo4[idx & 31];
        }
    }
    // fused pack_weights: 200 blocks x 512 threads = 102400 chunks
    if (blockIdx.x < 200) {
        int id = blockIdx.x * RT_BLOCK + tid;
        const float* src; ushort_t* dst; int Nn, ksteps, c;
        if (id < 32768) {            // W1
            int ee = id >> 12; c = id & 4095;
            Nn = HD; ksteps = 4; src = W1 + (size_t)ee * DIN * HD; dst = wt1f + (size_t)id * 8;
        } else if (id < 98304) {     // W2
            int t = id - 32768; int ee = t >> 13; c = t & 8191;
            Nn = HD; ksteps = 8; src = W2 + (size_t)ee * HD * HD; dst = wt2f + (size_t)t * 8;
        } else {                     // Wo
            int t = id - 98304; c = t;
            Nn = DOUT; ksteps = 8; src = Wo; dst = wotf + (size_t)t * 8;
        }
        int L = c & 63; int kc = c >> 6;
        int kstep = kc % ksteps; int ntile = kc / ksteps;
        int qq = L >> 4, mm = L & 15;
        int n = ntile * 16 + mm; int k0 = kstep * 32 + qq * 8;
        u16x8 v;
#pragma unroll
        for (int j = 0; j < 8; j++) v[j] = f2bf(src[(size_t)(k0 + j) * Nn + n]);
        *(u16x8*)dst = v;
    }
    __syncthreads();

    int e = tid & 7;
    int tl = tid >> 3;
    int n = blockIdx.x * RT_TPB + tl;
    const float4* xr = (const float4*)(x + (size_t)n * DIN);
    const float4* wv4 = (const float4*)(wgsT + e * 132);
    float lg = 0.f;
#pragma unroll
    for (int kk = 0; kk < 32; kk++) {
        float4 xv = xr[kk];
        float4 wv = wv4[kk];
        lg += xv.x * wv.x;
        lg += xv.y * wv.y;
        lg += xv.z * wv.z;
        lg += xv.w * wv.w;
    }
    // top-1 over the 8 lanes of this token (ties -> lowest expert index)
    float v0 = lg; int e0 = e;
#pragma unroll
    for (int d = 1; d < 8; d <<= 1) {
        float ov = __shfl_xor(v0, d, 64);
        int oe = __shfl_xor(e0, d, 64);
        if (ov > v0 || (ov == v0 && oe < e0)) { v0 = ov; e0 = oe; }
    }
    // top-2: mask out e0, reduce again
    float mv = (e == e0) ? -3.0e38f : lg;
    float v1 = mv; int e1 = e;
#pragma unroll
    for (int d = 1; d < 8; d <<= 1) {
        float ov = __shfl_xor(v1, d, 64);
        int oe = __shfl_xor(e1, d, 64);
        if (ov > v1 || (ov == v1 && oe < e1)) { v1 = ov; e1 = oe; }
    }
    float t = expf(v1 - v0);
    float inv = 1.0f / (1.0f + t);
    float w0 = inv, w1 = t * inv;

    bool writer = (e == 0);
    int p0 = 0, p1 = 0;
    if (writer) {
        p0 = atomicAdd(&lcnt[e0], 1);
        p1 = atomicAdd(&lcnt[e1], 1);
    }
    __syncthreads();
    if (tid < NEXP) lbase[tid] = atomicAdd(&counts[tid], lcnt[tid]);
    __syncthreads();
    if (writer) {
        int q0 = lbase[e0] + p0;
        list_tok[e0 * N_TOK + q0] = n;
        list_w[e0 * N_TOK + q0] = w0;
        int q1 = lbase[e1] + p1;
        list_tok[e1 * N_TOK + q1] = n;
        list_w[e1 * N_TOK + q1] = w1;
    }
}

// ---------------------------------------------------------------------------
// Fused per-expert MLP over 64-token tiles (bf16 MFMA, fp32 accumulate).
//
// h1/h2 LDS layout (bufH, 32KB): 4x16-subtiled for ds_read_b64_tr_b16:
//   byte(row,col) = (row>>4)*8192 + (col>>2)*128 + (col&3)*32 + (row&15)*2
// Epilogues: C-frag lane (q,mcol) holds rows q*4..q*4+3 at one col ->
//   2x v_cvt_pk_bf16_f32 + one ds_write_b64 (16 writes/thread, bank-uniform;
//   replaces 64 scalar conflicted ds_write_b16).
// GEMM2/3 A-frags: per (kstep,mt) chunk, group q reads its contiguous 128B
//   4x16 tile twice via ds_read_b64_tr_b16 (addr = base + q*256 + m*8,
//   offset:0 / offset:128) -> lane gets h[row=16mt+m][32k+8q+j], j=0..7.
// B-fragment global loads software-pipelined one kstep ahead.
// LDS total 48.5KB -> 3 blocks/CU.
// ---------------------------------------------------------------------------
__global__ __launch_bounds__(256, 3)
void expert_kernel(const float* __restrict__ x,
                   const int* __restrict__ counts,
                   const int* __restrict__ list_tok,
                   const float* __restrict__ list_w,
                   const ushort_t* __restrict__ wt1f,
                   const ushort_t* __restrict__ wt2f,
                   const ushort_t* __restrict__ wotf,
                   const float* __restrict__ b1,
                   const float* __restrict__ b2,
                   float* __restrict__ out) {
    int e = blockIdx.x & 7;
    int tile = blockIdx.x >> 3;
    int cnt = counts[e];
    int base = tile * MT;
    if (base >= cnt) return;
    int rows = cnt - base; if (rows > MT) rows = MT;

    __shared__ __align__(16) ushort_t bufA[8192];  // 16KB: x tile (A-frag layout)
    __shared__ __align__(16) ushort_t bufH[16384]; // 32KB: h1, then h2 (tr-tiled)
    __shared__ int toks_s[MT];
    __shared__ float wts_s[MT];

    int tid = threadIdx.x;
    int lane = tid & 63;
    int w = tid >> 6;
    int q = lane >> 4;
    int mcol = lane & 15;

    if (tid < MT) {
        int rr = tid < rows ? tid : rows - 1;
        toks_s[tid] = list_tok[(size_t)e * N_TOK + base + rr];
        wts_s[tid] = list_w[(size_t)e * N_TOK + base + rr];
    }

    // prefetch biases + GEMM1 kstep-0 B-frags early (overlap with staging)
    float bias1[4], bias2[4];
#pragma unroll
    for (int nt = 0; nt < 4; nt++) {
        int nn = (w * 4 + nt) * 16 + mcol;
        bias1[nt] = b1[e * HD + nn];
        bias2[nt] = b2[e * HD + nn];
    }
    const bf16x8* B1 = (const bf16x8*)(wt1f + (size_t)e * 4096 * 8);
    bf16x8 b1r[2][4];
#pragma unroll
    for (int nt = 0; nt < 4; nt++) b1r[0][nt] = B1[((w * 4 + nt) * 4 + 0) * 64 + lane];

    // stage x tile (fp32 -> bf16, packed conversion) into A-frag layout
    for (int c = tid; c < 1024; c += 256) {
        int row = c >> 4;
        int kchunk = c & 15;
        int rr = row < rows ? row : rows - 1;
        int tok = list_tok[(size_t)e * N_TOK + base + rr];
        const float4* src = (const float4*)(x + (size_t)tok * DIN + kchunk * 8);
        float4 lo = src[0], hi = src[1];
        unsigned p0, p1, p2, p3;
        asm("v_cvt_pk_bf16_f32 %0, %1, %2" : "=v"(p0) : "v"(lo.x), "v"(lo.y));
        asm("v_cvt_pk_bf16_f32 %0, %1, %2" : "=v"(p1) : "v"(lo.z), "v"(lo.w));
        asm("v_cvt_pk_bf16_f32 %0, %1, %2" : "=v"(p2) : "v"(hi.x), "v"(hi.y));
        asm("v_cvt_pk_bf16_f32 %0, %1, %2" : "=v"(p3) : "v"(hi.z), "v"(hi.w));
        int kstep = kchunk >> 2, qq = kchunk & 3;
        int dchunk = (kstep * 4 + (row >> 4)) * 64 + qq * 16 + (row & 15);
        u32x4 v; v.x = p0; v.y = p1; v.z = p2; v.w = p3;
        *(u32x4*)(&bufA[dchunk * 8]) = v;
    }
    __syncthreads();

    const bf16x8* Albs = (const bf16x8*)bufA;

    // ---- GEMM1: x[64x128] @ W1[128x256] -> h1 ----
    f32x4 acc[4][4];
#pragma unroll
    for (int mt = 0; mt < 4; mt++)
#pragma unroll
        for (int nt = 0; nt < 4; nt++) acc[mt][nt] = (f32x4){0.f, 0.f, 0.f, 0.f};
#pragma unroll
    for (int kstep = 0; kstep < 4; kstep++) {
        const int cur = kstep & 1, nxt = cur ^ 1;
        if (kstep < 3) {
#pragma unroll
            for (int nt = 0; nt < 4; nt++)
                b1r[nxt][nt] = B1[((w * 4 + nt) * 4 + kstep + 1) * 64 + lane];
        }
        bf16x8 a[4];
#pragma unroll
        for (int mt = 0; mt < 4; mt++) a[mt] = Albs[(kstep * 4 + mt) * 64 + lane];
#pragma unroll
        for (int nt = 0; nt < 4; nt++)
#pragma unroll
            for (int mt = 0; mt < 4; mt++)
                acc[mt][nt] = __builtin_amdgcn_mfma_f32_16x16x32_bf16(a[mt], b1r[cur][nt], acc[mt][nt], 0, 0, 0);
    }

    // prefetch GEMM2 kstep-0 B-frags (in flight across epilogue 1)
    const bf16x8* B2 = (const bf16x8*)(wt2f + (size_t)e * 8192 * 8);
    bf16x8 b2r[2][4];
#pragma unroll
    for (int nt = 0; nt < 4; nt++) b2r[0][nt] = B2[((w * 4 + nt) * 8 + 0) * 64 + lane];

    // epilogue 1: bias + relu -> bufH (h1), packed b64 stores
#pragma unroll
    for (int nt = 0; nt < 4; nt++) {
        int off0 = w * 2048 + nt * 512 + (mcol >> 2) * 128 + (mcol & 3) * 32 + q * 8;
#pragma unroll
        for (int mt = 0; mt < 4; mt++) {
            float v0 = acc[mt][nt][0] + bias1[nt]; v0 = v0 > 0.f ? v0 : 0.f;
            float v1 = acc[mt][nt][1] + bias1[nt]; v1 = v1 > 0.f ? v1 : 0.f;
            float v2 = acc[mt][nt][2] + bias1[nt]; v2 = v2 > 0.f ? v2 : 0.f;
            float v3 = acc[mt][nt][3] + bias1[nt]; v3 = v3 > 0.f ? v3 : 0.f;
            unsigned d0, d1;
            asm("v_cvt_pk_bf16_f32 %0, %1, %2" : "=v"(d0) : "v"(v0), "v"(v1));
            asm("v_cvt_pk_bf16_f32 %0, %1, %2" : "=v"(d1) : "v"(v2), "v"(v3));
            u32x2 dd; dd.x = d0; dd.y = d1;
            *(u32x2*)(&bufH[(mt * 8192 + off0) >> 1]) = dd;
        }
    }
    __syncthreads();

    // per-lane tr-read base: group q at +q*256, lane m supplies its own 8B
    unsigned trb = ((unsigned)(size_t)(void*)bufH) + (unsigned)(q * 256 + mcol * 8);

    // ---- GEMM2: h1[64x256] @ W2[256x256] -> h2 ----
    f32x4 acc2[4][4];
#pragma unroll
    for (int mt = 0; mt < 4; mt++)
#pragma unroll
        for (int nt = 0; nt < 4; nt++) acc2[mt][nt] = (f32x4){0.f, 0.f, 0.f, 0.f};
#pragma unroll
    for (int kstep = 0; kstep < 8; kstep++) {
        const int cur = kstep & 1, nxt = cur ^ 1;
        if (kstep < 7) {
#pragma unroll
            for (int nt = 0; nt < 4; nt++)
                b2r[nxt][nt] = B2[((w * 4 + nt) * 8 + kstep + 1) * 64 + lane];
        }
        bf16x8 a[4];
#pragma unroll
        for (int mt = 0; mt < 4; mt++) {
            bf16x4 lo, hi;
            unsigned ad = trb + (unsigned)(mt * 8192 + kstep * 1024);
            asm volatile("ds_read_b64_tr_b16 %0, %2\n\t"
                         "ds_read_b64_tr_b16 %1, %2 offset:128"
                         : "=&v"(lo), "=&v"(hi) : "v"(ad));
            a[mt] = __builtin_shufflevector(lo, hi, 0, 1, 2, 3, 4, 5, 6, 7);
        }
        asm volatile("s_waitcnt lgkmcnt(0)" ::: "memory");
        __builtin_amdgcn_sched_barrier(0);
#pragma unroll
        for (int nt = 0; nt < 4; nt++)
#pragma unroll
            for (int mt = 0; mt < 4; mt++)
                acc2[mt][nt] = __builtin_amdgcn_mfma_f32_16x16x32_bf16(a[mt], b2r[cur][nt], acc2[mt][nt], 0, 0, 0);
    }
    __syncthreads();  // all waves done reading h1 before overwriting bufH

    // prefetch GEMM3 kstep-0 B-frags (in flight across epilogue 2)
    const bf16x8* B3 = (const bf16x8*)wotf;
    bf16x8 b3r[2][2];
#pragma unroll
    for (int nt = 0; nt < 2; nt++) b3r[0][nt] = B3[((w * 2 + nt) * 8 + 0) * 64 + lane];

    // epilogue 2: bias + relu -> bufH (h2 over h1)
#pragma unroll
    for (int nt = 0; nt < 4; nt++) {
        int off0 = w * 2048 + nt * 512 + (mcol >> 2) * 128 + (mcol & 3) * 32 + q * 8;
#pragma unroll
        for (int mt = 0; mt < 4; mt++) {
            float v0 = acc2[mt][nt][0] + bias2[nt]; v0 = v0 > 0.f ? v0 : 0.f;
            float v1 = acc2[mt][nt][1] + bias2[nt]; v1 = v1 > 0.f ? v1 : 0.f;
            float v2 = acc2[mt][nt][2] + bias2[nt]; v2 = v2 > 0.f ? v2 : 0.f;
            float v3 = acc2[mt][nt][3] + bias2[nt]; v3 = v3 > 0.f ? v3 : 0.f;
            unsigned d0, d1;
            asm("v_cvt_pk_bf16_f32 %0, %1, %2" : "=v"(d0) : "v"(v0), "v"(v1));
            asm("v_cvt_pk_bf16_f32 %0, %1, %2" : "=v"(d1) : "v"(v2), "v"(v3));
            u32x2 dd; dd.x = d0; dd.y = d1;
            *(u32x2*)(&bufH[(mt * 8192 + off0) >> 1]) = dd;
        }
    }
    __syncthreads();

    // ---- GEMM3: h2[64x256] @ Wo[256x128] -> y; weighted atomic combine ----
    f32x4 acc3[4][2];
#pragma unroll
    for (int mt = 0; mt < 4; mt++)
#pragma unroll
        for (int nt = 0; nt < 2; nt++) acc3[mt][nt] = (f32x4){0.f, 0.f, 0.f, 0.f};
#pragma unroll
    for (int kstep = 0; kstep < 8; kstep++) {
        const int cur = kstep & 1, nxt = cur ^ 1;
        if (kstep < 7) {
#pragma unroll
            for (int nt = 0; nt < 2; nt++)
                b3r[nxt][nt] = B3[((w * 2 + nt) * 8 + kstep + 1) * 64 + lane];
        }
        bf16x8 a[4];
#pragma unroll
        for (int mt = 0; mt < 4; mt++) {
            bf16x4 lo, hi;
            unsigned ad = trb + (unsigned)(mt * 8192 + kstep * 1024);
            asm volatile("ds_read_b64_tr_b16 %0, %2\n\t"
                         "ds_read_b64_tr_b16 %1, %2 offset:128"
                         : "=&v"(lo), "=&v"(hi) : "v"(ad));
            a[mt] = __builtin_shufflevector(lo, hi, 0, 1, 2, 3, 4, 5, 6, 7);
        }
        asm volatile("s_waitcnt lgkmcnt(0)" ::: "memory");
        __builtin_amdgcn_sched_barrier(0);
#pragma unroll
        for (int nt = 0; nt < 2; nt++)
#pragma unroll
            for (int mt = 0; mt < 4; mt++)
                acc3[mt][nt] = __builtin_amdgcn_mfma_f32_16x16x32_bf16(a[mt], b3r[cur][nt], acc3[mt][nt], 0, 0, 0);
    }
#pragma unroll
    for (int mt = 0; mt < 4; mt++) {
#pragma unroll
        for (int r = 0; r < 4; r++) {
            int row = mt * 16 + q * 4 + r;
            if (row < rows) {
                int tok = toks_s[row];
                float wgt = wts_s[row];
                float* dst = out + (size_t)tok * DOUT;
#pragma unroll
                for (int nt = 0; nt < 2; nt++) {
                    int col = (w * 2 + nt) * 16 + mcol;
                    atomicAdd(&dst[col], wgt * acc3[mt][nt][r]);
                }
            }
        }
    }
}

extern "C" void kernel_launch(void* const* d_in, const int* in_sizes, int n_in,
                              void* d_out, int out_size, void* d_ws, size_t ws_size,
                              hipStream_t stream) {
    const float* x  = (const float*)d_in[0];
    const float* Wg = (const float*)d_in[1];
    const float* W1 = (const float*)d_in[2];
    const float* b1 = (const float*)d_in[3];
    const float* W2 = (const float*)d_in[4];
    const float* b2 = (const float*)d_in[5];
    const float* Wo = (const float*)d_in[6];
    const float* bo = (const float*)d_in[7];
    float* out = (float*)d_out;

    char* ws = (char*)d_ws;
    size_t off = 0;
    int* counts    = (int*)(ws + off);    off += 256;
    int* list_tok  = (int*)(ws + off);    off += (size_t)NEXP * N_TOK * 4;
    float* list_w  = (float*)(ws + off);  off += (size_t)NEXP * N_TOK * 4;
    ushort_t* wt1f = (ushort_t*)(ws + off); off += (size_t)NEXP * DIN * HD * 2;
    ushort_t* wt2f = (ushort_t*)(ws + off); off += (size_t)NEXP * HD * HD * 2;
    ushort_t* wotf = (ushort_t*)(ws + off); off += (size_t)HD * DOUT * 2;

    hipMemsetAsync(counts, 0, 256, stream);
    router_kernel<<<N_TOK / RT_TPB, RT_BLOCK, 0, stream>>>(
        x, Wg, W1, W2, Wo, bo, counts, list_tok, list_w, wt1f, wt2f, wotf, out);
    expert_kernel<<<NEXP * MAX_TILES, 256, 0, stream>>>(x, counts, list_tok, list_w,
                                                        wt1f, wt2f, wotf, b1, b2, out);
}